// Round 1
// baseline (3214.594 us; speedup 1.0000x reference)
//
#include <hip/hip_runtime.h>
#include <hip/hip_bf16.h>
#include <math.h>

// MoE MLP: B=4, S=2048, H=1024, D_FF=4096, E=8, top-2.
// Round 1: dense-equivalent (all experts over all tokens, scaled by combine
// weight) with m97-style bf16 MFMA GEMMs. Correctness-first.

#define TT  8192   // tokens = B*S
#define HD  1024   // hidden
#define DFF 4096   // ffn dim
#define NE  8      // experts

typedef __attribute__((ext_vector_type(8))) short short8;
typedef __attribute__((ext_vector_type(4))) float f32x4;

// fp32 -> bf16 round-to-nearest-even (finite inputs)
static __device__ __forceinline__ unsigned short f2bf(float f) {
    unsigned int u = __float_as_uint(f);
    unsigned int r = (u + 0x7fffu + ((u >> 16) & 1u)) >> 16;
    return (unsigned short)r;
}

// async global->LDS, 16 bytes per lane. LDS dest = wave-uniform base + lane*16.
static __device__ __forceinline__ void gload_lds16(const void* gp, void* lp) {
    __builtin_amdgcn_global_load_lds(
        (__attribute__((address_space(1))) void*)(void*)gp,
        (__attribute__((address_space(3))) void*)lp,
        16, 0, 0);
}

// ---------------------------------------------------------------- X -> bf16
__global__ __launch_bounds__(256) void cvt_x_kernel(const float* __restrict__ x,
                                                    unsigned short* __restrict__ xb) {
    const long i = (long)blockIdx.x * 256 + threadIdx.x;
    float4 v = ((const float4*)x)[i];
    ushort4 o;
    o.x = f2bf(v.x); o.y = f2bf(v.y); o.z = f2bf(v.z); o.w = f2bf(v.w);
    ((ushort4*)xb)[i] = o;
}

// ---------------------------------------------------------------- router
// One wave per token. fp64 accumulation so top-k selection matches the
// numpy reference ordering on near-ties (fp32 sum-order flips are ~10-20%
// likely across 8192 tokens and would blow the absmax threshold).
__global__ __launch_bounds__(256) void router_kernel(const float* __restrict__ x,
                                                     const float* __restrict__ wr,
                                                     float* __restrict__ cw) {
    const int token = blockIdx.x * 4 + (threadIdx.x >> 6);
    const int lane = threadIdx.x & 63;
    const float* xp = x + (long)token * HD;
    double lg[NE];
#pragma unroll
    for (int e = 0; e < NE; ++e) {
        const float* wp = wr + e * HD;
        double s = 0.0;
        for (int i = lane; i < HD; i += 64) s += (double)xp[i] * (double)wp[i];
#pragma unroll
        for (int off = 32; off > 0; off >>= 1) s += __shfl_xor(s, off, 64);
        lg[e] = s;
    }
    if (lane == 0) {
        int i0 = 0; double v0 = lg[0];
#pragma unroll
        for (int e = 1; e < NE; ++e) if (lg[e] > v0) { v0 = lg[e]; i0 = e; }
        int i1 = -1; double v1 = -1e300;
#pragma unroll
        for (int e = 0; e < NE; ++e) if (e != i0 && lg[e] > v1) { v1 = lg[e]; i1 = e; }
        double p = exp(v1 - v0);          // v1 <= v0
        double d = 1.0 + p;
        float w0 = (float)(1.0 / d);
        float w1 = (float)(p / d);
#pragma unroll
        for (int e = 0; e < NE; ++e)
            cw[token * NE + e] = (e == i0) ? w0 : ((e == i1) ? w1 : 0.f);
    }
}

// ---------------------------------------------------------------- GEMM (B^T)
// C[m,n] = sum_k A[m,k] * B[n,k].  A: bf16 [M,K] row-major. B: fp32 [N,K]
// row-major (the weight), converted to bf16 at fragment build.
// 128x128 block tile, BK=32, 4 waves (2x2), each wave 64x64 = 4x4 MFMA tiles.
// EPI=0: Hout[m,n] = bf16(gelu_exact(C + bias[n]))
// EPI=1: Out[m,n] += cw[m*8+expert] * (C + bias[n])
template <int EPI>
__global__ __launch_bounds__(256) void gemm_bt(
    const unsigned short* __restrict__ A,
    const float* __restrict__ B,
    const int M, const int N, const int K,
    unsigned short* __restrict__ Hout,
    const float* __restrict__ bias,
    float* __restrict__ Out,
    const float* __restrict__ cw,
    const int expert) {
    __shared__ unsigned short As[128 * 32];  // 8 KB  [m][k]
    __shared__ float Bs[128 * 32];           // 16 KB [n][k]

    const int tid = threadIdx.x;
    const int lane = tid & 63;
    const int quad = lane >> 4;
    const int l15 = lane & 15;
    const int wy = (tid >> 6) >> 1;
    const int wx = (tid >> 6) & 1;
    const long m0 = (long)blockIdx.x * 128;
    const long n0 = (long)blockIdx.y * 128;

    f32x4 acc[4][4];
#pragma unroll
    for (int i = 0; i < 4; ++i)
#pragma unroll
        for (int j = 0; j < 4; ++j) acc[i][j] = (f32x4){0.f, 0.f, 0.f, 0.f};

    for (int k0 = 0; k0 < K; k0 += 32) {
        // stage A tile: 128x32 bf16 = 8KB = 512 x 16B chunks (2 per thread)
        // chunk c: row = c>>2, k-off = (c&3)*8 ; LDS offset = c*16B (contiguous
        // per wave -> satisfies global_load_lds's uniform-base+lane*16 rule)
#pragma unroll
        for (int it = 0; it < 2; ++it) {
            const int c = it * 256 + tid;
            const unsigned short* gp = A + (m0 + (c >> 2)) * K + k0 + (c & 3) * 8;
            gload_lds16(gp, As + c * 8);
        }
        // stage B tile: 128x32 fp32 = 16KB = 1024 x 16B chunks (4 per thread)
        // chunk c: row = c>>3, k-off = (c&7)*4
#pragma unroll
        for (int it = 0; it < 4; ++it) {
            const int c = it * 256 + tid;
            const float* gp = B + (n0 + (c >> 3)) * (long)K + k0 + (c & 7) * 4;
            gload_lds16(gp, Bs + c * 4);
        }
        __syncthreads();  // drains vmcnt before barrier (compiler-emitted)

        // A fragments: A[m = l15][k = quad*8 + j]
        short8 af[4];
#pragma unroll
        for (int mi = 0; mi < 4; ++mi)
            af[mi] = *(const short8*)(As + (wy * 64 + mi * 16 + l15) * 32 + quad * 8);

#pragma unroll
        for (int ni = 0; ni < 4; ++ni) {
            const float* bp = Bs + (wx * 64 + ni * 16 + l15) * 32 + quad * 8;
            f32x4 b0 = *(const f32x4*)bp;
            f32x4 b1 = *(const f32x4*)(bp + 4);
            short8 bf;
            bf[0] = (short)f2bf(b0[0]); bf[1] = (short)f2bf(b0[1]);
            bf[2] = (short)f2bf(b0[2]); bf[3] = (short)f2bf(b0[3]);
            bf[4] = (short)f2bf(b1[0]); bf[5] = (short)f2bf(b1[1]);
            bf[6] = (short)f2bf(b1[2]); bf[7] = (short)f2bf(b1[3]);
#pragma unroll
            for (int mi = 0; mi < 4; ++mi)
                acc[mi][ni] = __builtin_amdgcn_mfma_f32_16x16x32_bf16(
                    af[mi], bf, acc[mi][ni], 0, 0, 0);
        }
        __syncthreads();
    }

    // epilogue: C/D layout row = quad*4 + r, col = l15 (verified m89/m91)
#pragma unroll
    for (int mi = 0; mi < 4; ++mi) {
        const long rbase = m0 + wy * 64 + mi * 16 + quad * 4;
#pragma unroll
        for (int ni = 0; ni < 4; ++ni) {
            const long col = n0 + wx * 64 + ni * 16 + l15;
            const float bcol = bias[col];
#pragma unroll
            for (int r = 0; r < 4; ++r) {
                const long row = rbase + r;
                const float v = acc[mi][ni][r] + bcol;
                if constexpr (EPI == 0) {
                    const float g = 0.5f * v * (1.0f + erff(v * 0.70710678f));
                    Hout[row * N + col] = f2bf(g);
                } else {
                    const float w = cw[row * NE + expert];
                    Out[row * N + col] += w * v;  // safe: expert launches serialize
                }
            }
        }
    }
}

// ---------------------------------------------------------------- launch
extern "C" void kernel_launch(void* const* d_in, const int* in_sizes, int n_in,
                              void* d_out, int out_size, void* d_ws, size_t ws_size,
                              hipStream_t stream) {
    const float* x  = (const float*)d_in[0];   // [4,2048,1024]
    const float* wr = (const float*)d_in[1];   // [8,1024]
    const float* w1 = (const float*)d_in[2];   // [8,4096,1024]
    const float* b1 = (const float*)d_in[3];   // [8,4096]
    const float* w2 = (const float*)d_in[4];   // [8,1024,4096]
    const float* b2 = (const float*)d_in[5];   // [8,1024]
    float* out = (float*)d_out;                // [4,2048,1024] fp32

    // workspace layout (~84 MB): Xb bf16 | H1 bf16 | cw fp32
    unsigned short* Xb = (unsigned short*)d_ws;                 // TT*HD
    unsigned short* H1 = Xb + (size_t)TT * HD;                  // TT*DFF
    float* cw = (float*)(H1 + (size_t)TT * DFF);                // TT*NE

    hipMemsetAsync(d_out, 0, sizeof(float) * (size_t)TT * HD, stream);
    cvt_x_kernel<<<dim3(TT * HD / 4 / 256), dim3(256), 0, stream>>>(x, Xb);
    router_kernel<<<dim3(TT / 4), dim3(256), 0, stream>>>(x, wr, cw);

    for (int e = 0; e < NE; ++e) {
        // FC1: h1 = gelu(X @ w1[e]^T + b1[e])   M=8192 N=4096 K=1024
        gemm_bt<0><<<dim3(TT / 128, DFF / 128), dim3(256), 0, stream>>>(
            Xb, w1 + (size_t)e * DFF * HD, TT, DFF, HD,
            H1, b1 + (size_t)e * DFF, nullptr, nullptr, e);
        // FC2: out += cw[:,e] * (h1 @ w2[e]^T + b2[e])   M=8192 N=1024 K=4096
        gemm_bt<1><<<dim3(TT / 128, HD / 128), dim3(256), 0, stream>>>(
            H1, w2 + (size_t)e * HD * DFF, TT, HD, DFF,
            nullptr, b2 + (size_t)e * HD, out, cw, e);
    }
}

// Round 2
// 1187.169 us; speedup vs baseline: 2.7078x; 2.7078x over previous
//
#include <hip/hip_runtime.h>
#include <hip/hip_bf16.h>
#include <math.h>

// MoE MLP: B=4, S=2048, H=1024, D_FF=4096, E=8, top-2.
// Round 2: sparse grouped GEMM (gather top-2 rows per expert, 4x FLOP cut)
// + bf16 weight pre-conversion (removes inline cvt VALU bottleneck; GEMM is
// the verified m97 structure: 128x128 tile, BK=32, global_load_lds w=16,
// ds_read_b128 fragments, 16x16x32_bf16 MFMA).

#define TT  8192    // tokens = B*S
#define HD  1024    // hidden
#define DFF 4096    // ffn dim
#define NE  8       // experts
#define ROWCAP 17408   // 16384 gathered rows + per-expert pad to 128 (<= 17400)
#define MAXTILES 136   // sum ceil(counts[e]/128) <= 135

typedef __attribute__((ext_vector_type(8))) short short8;
typedef __attribute__((ext_vector_type(4))) float f32x4;

// fp32 -> bf16 round-to-nearest-even (finite inputs)
static __device__ __forceinline__ unsigned short f2bf(float f) {
    unsigned int u = __float_as_uint(f);
    unsigned int r = (u + 0x7fffu + ((u >> 16) & 1u)) >> 16;
    return (unsigned short)r;
}

// async global->LDS, 16 bytes per lane. LDS dest = wave-uniform base + lane*16.
static __device__ __forceinline__ void gload_lds16(const void* gp, void* lp) {
    __builtin_amdgcn_global_load_lds(
        (__attribute__((address_space(1))) void*)(void*)gp,
        (__attribute__((address_space(3))) void*)lp,
        16, 0, 0);
}

// ------------------------------------------------------------- weights -> bf16
__global__ __launch_bounds__(256) void cvt_w_kernel(const float* __restrict__ s,
                                                    unsigned short* __restrict__ d) {
    const long i = (long)blockIdx.x * 256 + threadIdx.x;
    float4 v = ((const float4*)s)[i];
    ushort4 o;
    o.x = f2bf(v.x); o.y = f2bf(v.y); o.z = f2bf(v.z); o.w = f2bf(v.w);
    ((ushort4*)d)[i] = o;
}

// ------------------------------------------------------------- router
// One wave per token; fp64 logits so top-k selection matches numpy ordering
// on near-ties (verified passing in round 1).
__global__ __launch_bounds__(256) void router_kernel(const float* __restrict__ x,
                                                     const float* __restrict__ wr,
                                                     int* __restrict__ tokE,
                                                     float* __restrict__ tokW,
                                                     int* __restrict__ counts) {
    const int token = blockIdx.x * 4 + (threadIdx.x >> 6);
    const int lane = threadIdx.x & 63;
    const float* xp = x + (long)token * HD;
    double lg[NE];
#pragma unroll
    for (int e = 0; e < NE; ++e) {
        const float* wp = wr + e * HD;
        double s = 0.0;
        for (int i = lane; i < HD; i += 64) s += (double)xp[i] * (double)wp[i];
#pragma unroll
        for (int off = 32; off > 0; off >>= 1) s += __shfl_xor(s, off, 64);
        lg[e] = s;
    }
    if (lane == 0) {
        int i0 = 0; double v0 = lg[0];
#pragma unroll
        for (int e = 1; e < NE; ++e) if (lg[e] > v0) { v0 = lg[e]; i0 = e; }
        int i1 = -1; double v1 = -1e300;
#pragma unroll
        for (int e = 0; e < NE; ++e) if (e != i0 && lg[e] > v1) { v1 = lg[e]; i1 = e; }
        double p = exp(v1 - v0);  // v1 <= v0
        double d = 1.0 + p;
        tokE[token * 2] = i0;     tokW[token * 2] = (float)(1.0 / d);
        tokE[token * 2 + 1] = i1; tokW[token * 2 + 1] = (float)(p / d);
        atomicAdd(&counts[i0], 1);
        atomicAdd(&counts[i1], 1);
    }
}

// ------------------------------------------------------------- tile map setup
// Single-thread scan over 8 experts: per-expert row offsets (padded to 128)
// + tile->(expert, row0) map. <200 iterations, negligible.
__global__ void setup_kernel(const int* __restrict__ counts,
                             int* __restrict__ cursor,
                             int* __restrict__ tileExpert,
                             int* __restrict__ tileRow0) {
    if (threadIdx.x == 0 && blockIdx.x == 0) {
        int off = 0, t = 0;
        for (int e = 0; e < NE; ++e) {
            cursor[e] = off;
            const int padded = (counts[e] + 127) & ~127;
            for (int i = 0; i < padded / 128; ++i) {
                tileExpert[t] = e;
                tileRow0[t] = off + i * 128;
                ++t;
            }
            off += padded;
        }
        for (; t < MAXTILES; ++t) tileExpert[t] = -1;
    }
}

// default pad rows: token 0, weight 0 (keeps everything defined; cw=0 kills it)
__global__ __launch_bounds__(256) void init_rows_kernel(int* __restrict__ rowTok,
                                                        float* __restrict__ rowCw) {
    const int i = blockIdx.x * 256 + threadIdx.x;
    rowTok[i] = 0;
    rowCw[i] = 0.f;
}

__global__ __launch_bounds__(256) void scatter_kernel(const int* __restrict__ tokE,
                                                      const float* __restrict__ tokW,
                                                      int* __restrict__ cursor,
                                                      int* __restrict__ rowTok,
                                                      float* __restrict__ rowCw) {
    const int t = blockIdx.x * 256 + threadIdx.x;
#pragma unroll
    for (int j = 0; j < 2; ++j) {
        const int e = tokE[t * 2 + j];
        const int pos = atomicAdd(&cursor[e], 1);
        rowTok[pos] = t;
        rowCw[pos] = tokW[t * 2 + j];
    }
}

// gather + cvt: Xg[row][:] = bf16(x[rowTok[row]][:])
__global__ __launch_bounds__(256) void gather_kernel(const float* __restrict__ x,
                                                     const int* __restrict__ rowTok,
                                                     unsigned short* __restrict__ Xg) {
    const int row = blockIdx.x;
    const int tok = rowTok[row];
    const float4 v = ((const float4*)(x + (long)tok * HD))[threadIdx.x];
    ushort4 o;
    o.x = f2bf(v.x); o.y = f2bf(v.y); o.z = f2bf(v.z); o.w = f2bf(v.w);
    ((ushort4*)(Xg + (long)row * HD))[threadIdx.x] = o;
}

// ------------------------------------------------------------- grouped GEMM
// C[m,n] = sum_k A[row0+m,k] * W[e][n0+n,k], both bf16, m97 structure.
// EPI=0: Hout[row, col] = bf16(gelu_exact(C + bias))
// EPI=1: atomicAdd(Out[rowTok[row]*HD + col], rowCw[row] * (C + bias))
template <int EPI, int N, int K>
__global__ __launch_bounds__(256) void gemm_moe(
    const unsigned short* __restrict__ A,
    const unsigned short* __restrict__ W,
    const int* __restrict__ tileExpert,
    const int* __restrict__ tileRow0,
    unsigned short* __restrict__ Hout,
    const float* __restrict__ bias,
    float* __restrict__ Out,
    const float* __restrict__ rowCw,
    const int* __restrict__ rowTok) {
    const int e = tileExpert[blockIdx.x];
    if (e < 0) return;

    __shared__ unsigned short As[128 * 32];  // 8 KB [m][k]
    __shared__ unsigned short Bs[128 * 32];  // 8 KB [n][k]

    const int tid = threadIdx.x;
    const int lane = tid & 63;
    const int quad = lane >> 4;
    const int l15 = lane & 15;
    const int wy = (tid >> 6) >> 1;
    const int wx = (tid >> 6) & 1;
    const long row0 = tileRow0[blockIdx.x];
    const long n0 = (long)blockIdx.y * 128;
    const unsigned short* Ab = A + row0 * K;
    const unsigned short* Bb = W + ((long)e * N + n0) * K;

    f32x4 acc[4][4];
#pragma unroll
    for (int i = 0; i < 4; ++i)
#pragma unroll
        for (int j = 0; j < 4; ++j) acc[i][j] = (f32x4){0.f, 0.f, 0.f, 0.f};

    for (int k0 = 0; k0 < K; k0 += 32) {
        // each tile: 128x32 bf16 = 8 KB = 512 x 16B chunks -> 2 per thread.
        // chunk c: row = c>>2, k-off = (c&3)*8; LDS dest = c*16B (contiguous
        // per wave -> satisfies the uniform-base + lane*16 rule).
#pragma unroll
        for (int it = 0; it < 2; ++it) {
            const int c = it * 256 + tid;
            gload_lds16(Ab + (long)(c >> 2) * K + k0 + (c & 3) * 8, As + c * 8);
            gload_lds16(Bb + (long)(c >> 2) * K + k0 + (c & 3) * 8, Bs + c * 8);
        }
        __syncthreads();

        // A/B fragments: [m = l15][k = quad*8 + j]
        short8 af[4];
#pragma unroll
        for (int mi = 0; mi < 4; ++mi)
            af[mi] = *(const short8*)(As + (wy * 64 + mi * 16 + l15) * 32 + quad * 8);
#pragma unroll
        for (int ni = 0; ni < 4; ++ni) {
            const short8 bf = *(const short8*)(Bs + (wx * 64 + ni * 16 + l15) * 32 + quad * 8);
#pragma unroll
            for (int mi = 0; mi < 4; ++mi)
                acc[mi][ni] = __builtin_amdgcn_mfma_f32_16x16x32_bf16(
                    af[mi], bf, acc[mi][ni], 0, 0, 0);
        }
        __syncthreads();
    }

    // epilogue: C/D layout row = quad*4 + r, col = l15 (verified m89/m91)
#pragma unroll
    for (int mi = 0; mi < 4; ++mi) {
        const int lrow0 = wy * 64 + mi * 16 + quad * 4;
#pragma unroll
        for (int ni = 0; ni < 4; ++ni) {
            const long col = n0 + wx * 64 + ni * 16 + l15;
            const float bcol = bias[(long)e * N + col];
#pragma unroll
            for (int r = 0; r < 4; ++r) {
                const long grow = row0 + lrow0 + r;
                const float v = acc[mi][ni][r] + bcol;
                if constexpr (EPI == 0) {
                    const float g = 0.5f * v * (1.0f + erff(v * 0.70710678f));
                    Hout[grow * N + col] = f2bf(g);
                } else {
                    const float w = rowCw[grow];
                    if (w != 0.f)
                        atomicAdd(&Out[(long)rowTok[grow] * HD + col], w * v);
                }
            }
        }
    }
}

// ------------------------------------------------------------- launch
extern "C" void kernel_launch(void* const* d_in, const int* in_sizes, int n_in,
                              void* d_out, int out_size, void* d_ws, size_t ws_size,
                              hipStream_t stream) {
    const float* x  = (const float*)d_in[0];   // [4,2048,1024]
    const float* wr = (const float*)d_in[1];   // [8,1024]
    const float* w1 = (const float*)d_in[2];   // [8,4096,1024]
    const float* b1 = (const float*)d_in[3];   // [8,4096]
    const float* w2 = (const float*)d_in[4];   // [8,1024,4096]
    const float* b2 = (const float*)d_in[5];   // [8,1024]
    float* out = (float*)d_out;                // [4,2048,1024] fp32

    // workspace layout (~246 MB)
    char* p = (char*)d_ws;
    auto alloc = [&](size_t bytes) {
        char* r = p;
        p += (bytes + 255) & ~(size_t)255;
        return r;
    };
    unsigned short* Xg  = (unsigned short*)alloc((size_t)ROWCAP * HD * 2);   // 35.7 MB
    unsigned short* H1g = (unsigned short*)alloc((size_t)ROWCAP * DFF * 2);  // 142.6 MB
    unsigned short* Wb  = (unsigned short*)alloc((size_t)NE * DFF * HD * 2); // 67.1 MB (reused w1/w2)
    float* rowCw   = (float*)alloc((size_t)ROWCAP * 4);
    int*   rowTok  = (int*)alloc((size_t)ROWCAP * 4);
    int*   tokE    = (int*)alloc((size_t)TT * 2 * 4);
    float* tokW    = (float*)alloc((size_t)TT * 2 * 4);
    int*   counts  = (int*)alloc(64);
    int*   cursor  = (int*)alloc(64);
    int*   tileExpert = (int*)alloc(MAXTILES * 4);
    int*   tileRow0   = (int*)alloc(MAXTILES * 4);

    hipMemsetAsync(out, 0, sizeof(float) * (size_t)TT * HD, stream);
    hipMemsetAsync(counts, 0, 64, stream);

    router_kernel<<<dim3(TT / 4), dim3(256), 0, stream>>>(x, wr, tokE, tokW, counts);
    setup_kernel<<<dim3(1), dim3(64), 0, stream>>>(counts, cursor, tileExpert, tileRow0);
    init_rows_kernel<<<dim3(ROWCAP / 256), dim3(256), 0, stream>>>(rowTok, rowCw);
    scatter_kernel<<<dim3(TT / 256), dim3(256), 0, stream>>>(tokE, tokW, cursor, rowTok, rowCw);
    gather_kernel<<<dim3(ROWCAP), dim3(256), 0, stream>>>(x, rowTok, Xg);

    // FC1: H1g = gelu(Xg @ w1[e]^T + b1[e]) over gathered rows
    cvt_w_kernel<<<dim3(NE * DFF * HD / 4 / 256), dim3(256), 0, stream>>>(w1, Wb);
    gemm_moe<0, DFF, HD><<<dim3(MAXTILES, DFF / 128), dim3(256), 0, stream>>>(
        Xg, Wb, tileExpert, tileRow0, H1g, b1, nullptr, nullptr, nullptr);

    // FC2: out[tok] += cw * (H1g @ w2[e]^T + b2[e])
    cvt_w_kernel<<<dim3(NE * HD * DFF / 4 / 256), dim3(256), 0, stream>>>(w2, Wb);
    gemm_moe<1, HD, DFF><<<dim3(MAXTILES, HD / 128), dim3(256), 0, stream>>>(
        H1g, Wb, tileExpert, tileRow0, nullptr, b2, out, rowCw, rowTok);
}